// Round 5
// baseline (161.692 us; speedup 1.0000x reference)
//
#include <hip/hip_runtime.h>
#include <math.h>

typedef __attribute__((ext_vector_type(8))) short short8;
typedef __attribute__((ext_vector_type(4))) float f32x4;
typedef unsigned int uint;
typedef unsigned short ushort;

#define T1 4.0f
#define T2 5.0f
#define T3 10.0f
#define EPSF 1e-8f
#define SST 68   // S^T / yT row stride (floats): rows 16B-aligned

__device__ inline ushort f2bf(float x) {
    union { float f; uint u; } a; a.f = x;
    uint r = a.u + 0x7FFFu + ((a.u >> 16) & 1u);
    return (ushort)(r >> 16);
}
__device__ inline float bf2f(ushort h) {
    union { uint u; float f; } a; a.u = ((uint)h) << 16;
    return a.f;
}

// async global->LDS, 16B per lane; LDS dest is wave-uniform base + lane*16
#define GLDS(gsrc, ldst) \
    __builtin_amdgcn_global_load_lds( \
        (const __attribute__((address_space(1))) uint*)(gsrc), \
        (__attribute__((address_space(3))) uint*)(ldst), 16, 0, 0)

// ---------------- prep v2: fp32 -> bf16 hi/lo planes, coalesced (+ w1 norms) ----------------
// Plane layout per idx: [kc 0..15][r 0..63][4 chunks of 16B, logical chunk c at
// physical slot (c + (r>>1)) & 3]  => 65536 B per idx.
// Block = (tensor, idx, rowhalf): 32 rows. Wave = contiguous half-row (1KB) per iter.
__global__ __launch_bounds__(256) void prep_kernel(
        const float* __restrict__ ecg, const float* __restrict__ sent,
        char* __restrict__ EH, char* __restrict__ EL,
        char* __restrict__ SH, char* __restrict__ SL, float* __restrict__ w1) {
    __shared__ float rs[32][2];
    const int bid = blockIdx.x;
    const int tensor = bid >> 7, idx = (bid >> 1) & 63, half = bid & 1;
    const float* src = (tensor ? sent : ecg) + (size_t)idx * 32768;
    char* dh = (tensor ? SH : EH) + (size_t)idx * 65536;
    char* dl = (tensor ? SL : EL) + (size_t)idx * 65536;
    const int tid = threadIdx.x;
    const int w = tid >> 6, l = tid & 63;

    if (tid < 64) { rs[tid >> 1][tid & 1] = 0.f; }
    __syncthreads();

    const int kc   = 8 * (w & 1) + (l >> 3);
    const int c    = (l >> 1) & 3;
    const int col  = 256 * (w & 1) + l * 4;
    const int wsel = w & 1;

    #pragma unroll
    for (int g = 0; g < 16; g++) {
        int r = 32 * half + 2 * g + (w >> 1);
        float4 v = *(const float4*)(src + (size_t)r * 512 + col);
        ushort h0 = f2bf(v.x), h1 = f2bf(v.y), h2 = f2bf(v.z), h3 = f2bf(v.w);
        uint2 H; H.x = (uint)h0 | ((uint)h1 << 16); H.y = (uint)h2 | ((uint)h3 << 16);
        ushort l0 = f2bf(v.x - bf2f(h0)), l1 = f2bf(v.y - bf2f(h1));
        ushort l2 = f2bf(v.z - bf2f(h2)), l3 = f2bf(v.w - bf2f(h3));
        uint2 L; L.x = (uint)l0 | ((uint)l1 << 16); L.y = (uint)l2 | ((uint)l3 << 16);
        size_t off = (size_t)kc * 4096 + r * 64 + ((c + (r >> 1)) & 3) * 16 + (l & 1) * 8;
        *(uint2*)(dh + off) = H;
        *(uint2*)(dl + off) = L;
        if (tensor) {
            float p = v.x * v.x + v.y * v.y + v.z * v.z + v.w * v.w;
            #pragma unroll
            for (int o = 32; o; o >>= 1) p += __shfl_xor(p, o);
            if (l == 0) rs[2 * g + (w >> 1)][wsel] += p;
        }
    }
    __syncthreads();
    if (tensor && tid < 32)
        w1[idx * 64 + 32 * half + tid] = sqrtf(rs[tid][0] + rs[tid][1]);
}

// ---------------- G_j = E_j E_j^T via 3-term bf16 MFMA from prepped planes ----------------
// Output layout: row t (128B), element u at phys chunk ((u>>3)+t)&7; lo plane +8192.
__global__ __launch_bounds__(256) void gprep_kernel(
        const char* __restrict__ EH, const char* __restrict__ EL, char* __restrict__ Gp) {
    __shared__ __align__(16) char lds[8192];
    const int j = blockIdx.x;
    const int tid = threadIdx.x;
    const int wv = tid >> 6, lane = tid & 63;
    const int wq = wv >> 1, wn = wv & 1;
    const int quad = lane >> 4, ln = lane & 15;
    const char* srcH = EH + (size_t)j * 65536 + wv * 1024 + lane * 16;
    const char* srcL = EL + (size_t)j * 65536 + wv * 1024 + lane * 16;

    int ao[2], bo[2];
    #pragma unroll
    for (int mi = 0; mi < 2; mi++) {
        int R = 32 * wq + 16 * mi + ln;
        ao[mi] = R * 64 + ((quad + (R >> 1)) & 3) * 16;
    }
    #pragma unroll
    for (int ni = 0; ni < 2; ni++) {
        int R = 32 * wn + 16 * ni + ln;
        bo[ni] = R * 64 + ((quad + (R >> 1)) & 3) * 16;
    }

    f32x4 acc[2][2];
    #pragma unroll
    for (int a = 0; a < 2; a++)
        #pragma unroll
        for (int b = 0; b < 2; b++) acc[a][b] = (f32x4){0.f, 0.f, 0.f, 0.f};

    for (int kc = 0; kc < 16; kc++) {
        GLDS(srcH + (size_t)kc * 4096, lds + wv * 1024);
        GLDS(srcL + (size_t)kc * 4096, lds + 4096 + wv * 1024);
        __syncthreads();
        short8 ah[2], al[2], bh[2], bl[2];
        #pragma unroll
        for (int mi = 0; mi < 2; mi++) {
            ah[mi] = *(const short8*)(lds + ao[mi]);
            al[mi] = *(const short8*)(lds + 4096 + ao[mi]);
        }
        #pragma unroll
        for (int ni = 0; ni < 2; ni++) {
            bh[ni] = *(const short8*)(lds + bo[ni]);
            bl[ni] = *(const short8*)(lds + 4096 + bo[ni]);
        }
        #pragma unroll
        for (int mi = 0; mi < 2; mi++)
            #pragma unroll
            for (int ni = 0; ni < 2; ni++) {
                acc[mi][ni] = __builtin_amdgcn_mfma_f32_16x16x32_bf16(ah[mi], bh[ni], acc[mi][ni], 0, 0, 0);
                acc[mi][ni] = __builtin_amdgcn_mfma_f32_16x16x32_bf16(ah[mi], bl[ni], acc[mi][ni], 0, 0, 0);
                acc[mi][ni] = __builtin_amdgcn_mfma_f32_16x16x32_bf16(al[mi], bh[ni], acc[mi][ni], 0, 0, 0);
            }
        __syncthreads();
    }
    #pragma unroll
    for (int mi = 0; mi < 2; mi++)
        #pragma unroll
        for (int ni = 0; ni < 2; ni++)
            #pragma unroll
            for (int r = 0; r < 4; r++) {
                int t = 32 * wq + 16 * mi + quad * 4 + r;
                int u = 32 * wn + 16 * ni + ln;
                float g = acc[mi][ni][r];
                ushort h = f2bf(g);
                ushort l = f2bf(g - bf2f(h));
                char* base = Gp + (size_t)j * 16384 + t * 128 + (((u >> 3) + t) & 7) * 16 + (u & 7) * 2;
                *(ushort*)base = h;
                *(ushort*)(base + 8192) = l;
            }
}

// ---------------- main: one block per 2x2 pairs (128x128 GEMM1 tile) ----------------
__global__ __launch_bounds__(256, 4) void pair_kernel(
        const char* __restrict__ EH, const char* __restrict__ EL,
        const char* __restrict__ SH, const char* __restrict__ SL,
        const char* __restrict__ Gp, const float* __restrict__ w1g,
        float* __restrict__ simval, float* __restrict__ out) {

    // lds: GEMM staging [EH 8K|EL 8K|SH 8K|SL 8K]=32K; then region0 = SsT(64x68 f32)/G(16K)/yT,
    // P (Phi 8K + Plo 8K) at 17408..33792
    __shared__ __align__(16) char lds[33792];
    __shared__ __align__(16) float mz[64];
    __shared__ float w12all[256], w2all[256];
    __shared__ float mpart[64][2], spart[64][2];

    const int tid = threadIdx.x;
    // XCD-aware mapping
    const int bn = blockIdx.x;
    const int xcd = bn & 7, slot = bn >> 3;
    const int T = xcd * 8 + (slot >> 4);
    const int wp = slot & 15;
    const int bi = (T >> 3) * 4 + (wp >> 2);
    const int bj = (T & 7) * 4 + (wp & 3);
    const int i0 = bi * 2, j0 = bj * 2;

    const int wv = tid >> 6, lane = tid & 63;
    const int wq = wv >> 1, wn = wv & 1;
    const int quad = lane >> 4, ln = lane & 15;

    int aoff[4], boff[4];
    #pragma unroll
    for (int mi = 0; mi < 4; mi++) {
        int R = 64 * (mi >> 1) + 32 * wq + 16 * (mi & 1) + ln;
        aoff[mi] = R * 64 + ((quad + (R >> 1)) & 3) * 16;
    }
    #pragma unroll
    for (int ni = 0; ni < 4; ni++) {
        int R = 64 * (ni >> 1) + 32 * wn + 16 * (ni & 1) + ln;
        boff[ni] = 16384 + R * 64 + ((quad + (R >> 1)) & 3) * 16;
    }

    const char* gA; const char* gB; int ldoff;
    if (wv == 0)      { gA = EH + (size_t)j0 * 65536;       gB = EH + (size_t)(j0 + 1) * 65536; ldoff = 0; }
    else if (wv == 1) { gA = EL + (size_t)j0 * 65536;       gB = EL + (size_t)(j0 + 1) * 65536; ldoff = 8192; }
    else if (wv == 2) { gA = SH + (size_t)i0 * 65536;       gB = SH + (size_t)(i0 + 1) * 65536; ldoff = 16384; }
    else              { gA = SL + (size_t)i0 * 65536;       gB = SL + (size_t)(i0 + 1) * 65536; ldoff = 24576; }
    gA += lane * 16; gB += lane * 16;

    f32x4 acc[4][4];
    #pragma unroll
    for (int a = 0; a < 4; a++)
        #pragma unroll
        for (int b = 0; b < 4; b++) acc[a][b] = (f32x4){0.f, 0.f, 0.f, 0.f};

    for (int kc = 0; kc < 16; kc++) {
        #pragma unroll
        for (int n = 0; n < 4; n++) GLDS(gA + n * 1024, lds + ldoff + n * 1024);
        #pragma unroll
        for (int n = 0; n < 4; n++) GLDS(gB + n * 1024, lds + ldoff + 4096 + n * 1024);
        gA += 4096; gB += 4096;
        __syncthreads();
        short8 bh[4], bl[4];
        #pragma unroll
        for (int ni = 0; ni < 4; ni++) {
            bh[ni] = *(const short8*)(lds + boff[ni]);
            bl[ni] = *(const short8*)(lds + boff[ni] + 8192);
        }
        #pragma unroll
        for (int mi = 0; mi < 4; mi++) {
            short8 ah = *(const short8*)(lds + aoff[mi]);
            short8 al = *(const short8*)(lds + aoff[mi] + 8192);
            #pragma unroll
            for (int ni = 0; ni < 4; ni++) {
                acc[mi][ni] = __builtin_amdgcn_mfma_f32_16x16x32_bf16(ah, bh[ni], acc[mi][ni], 0, 0, 0);
                acc[mi][ni] = __builtin_amdgcn_mfma_f32_16x16x32_bf16(ah, bl[ni], acc[mi][ni], 0, 0, 0);
                acc[mi][ni] = __builtin_amdgcn_mfma_f32_16x16x32_bf16(al, bh[ni], acc[mi][ni], 0, 0, 0);
            }
        }
        __syncthreads();
    }

    float* SsT = (float*)lds;          // [q][s], stride SST
    float* yT  = (float*)lds;          // [t][q], stride SST (aliases)
    char*  Pb  = lds + 17408;          // Phi 8K + Plo 8K

    #pragma unroll
    for (int pr = 0; pr < 4; pr++) {
        const int a = pr >> 1, b = pr & 1;
        const int i = i0 + b, j = j0 + a;

        // C-write: SsT[q][s0..s0+3] b128; plus register softmax1 partials
        #pragma unroll
        for (int dm = 0; dm < 2; dm++)
            #pragma unroll
            for (int dn = 0; dn < 2; dn++) {
                int s0 = 32 * wq + 16 * dm + quad * 4;
                int q  = 32 * wn + 16 * dn + ln;
                *(f32x4*)(SsT + q * SST + s0) = acc[2 * a + dm][2 * b + dn];
            }
        // softmax1 partial (this wave's 32 q) per s-row, in registers
        #pragma unroll
        for (int dm = 0; dm < 2; dm++)
            #pragma unroll
            for (int r = 0; r < 4; r++) {
                float v0 = acc[2 * a + dm][2 * b + 0][r];
                float v1 = acc[2 * a + dm][2 * b + 1][r];
                float m = fmaxf(v0, v1);
                m = fmaxf(m, __shfl_xor(m, 1));
                m = fmaxf(m, __shfl_xor(m, 2));
                m = fmaxf(m, __shfl_xor(m, 4));
                m = fmaxf(m, __shfl_xor(m, 8));
                float e = __expf(v0 - m) + __expf(v1 - m);
                e += __shfl_xor(e, 1);
                e += __shfl_xor(e, 2);
                e += __shfl_xor(e, 4);
                e += __shfl_xor(e, 8);
                if (ln == 0) {
                    int s = 32 * wq + 16 * dm + quad * 4 + r;
                    mpart[s][wn] = m;
                    spart[s][wn] = e;
                }
            }
        __syncthreads();

        // combine halves: mz[s] = m + ln(Z)
        if (tid < 64) {
            float m0 = mpart[tid][0], m1 = mpart[tid][1];
            float mm = fmaxf(m0, m1);
            float z = spart[tid][0] * __expf(m0 - mm) + spart[tid][1] * __expf(m1 - mm);
            mz[tid] = mm + __logf(z);
        }
        __syncthreads();

        // softmax2 over s (rows of SsT): P[q][s]; w12 fold in-reg; att_maps; pack P hi/lo
        {
            const int q = tid >> 2, c = tid & 3;
            float sc[16], at[16];
            #pragma unroll
            for (int r4 = 0; r4 < 4; r4++)
                *(f32x4*)(sc + 4 * r4) = *(const f32x4*)(SsT + q * SST + 16 * c + 4 * r4);
            float mzv[16];
            #pragma unroll
            for (int r4 = 0; r4 < 4; r4++)
                *(f32x4*)(mzv + 4 * r4) = *(const f32x4*)(mz + 16 * c + 4 * r4);
            float m2 = -1e30f;
            #pragma unroll
            for (int t = 0; t < 16; t++) {
                at[t] = __expf(sc[t] - mzv[t]);     // attn1
                m2 = fmaxf(m2, T1 * at[t]);
            }
            m2 = fmaxf(m2, __shfl_xor(m2, 1));
            m2 = fmaxf(m2, __shfl_xor(m2, 2));
            float sum = 0.f;
            #pragma unroll
            for (int t = 0; t < 16; t++) { at[t] = __expf(T1 * at[t] - m2); sum += at[t]; }
            sum += __shfl_xor(sum, 1);
            sum += __shfl_xor(sum, 2);
            float inv = 1.f / sum;
            float p12 = 0.f;
            #pragma unroll
            for (int t = 0; t < 16; t++) { at[t] *= inv; p12 += at[t] * sc[t]; }
            p12 += __shfl_xor(p12, 1);
            p12 += __shfl_xor(p12, 2);
            if (c == 0) w12all[pr * 64 + q] = p12;

            if (i == j) {
                float* om = out + 1 + (size_t)i * 4096;
                #pragma unroll
                for (int t = 0; t < 16; t++) om[q * 64 + c * 16 + t] = at[t];
            }

            uint hw[8], lw[8];
            #pragma unroll
            for (int e = 0; e < 8; e++) {
                ushort h0 = f2bf(at[2 * e]), h1 = f2bf(at[2 * e + 1]);
                hw[e] = (uint)h0 | ((uint)h1 << 16);
                ushort l0 = f2bf(at[2 * e] - bf2f(h0)), l1 = f2bf(at[2 * e + 1] - bf2f(h1));
                lw[e] = (uint)l0 | ((uint)l1 << 16);
            }
            int p0 = (2 * c + q) & 7, p1 = (2 * c + 1 + q) & 7;
            uint4 W;
            W.x = hw[0]; W.y = hw[1]; W.z = hw[2]; W.w = hw[3];
            *(uint4*)(Pb + q * 128 + p0 * 16) = W;
            W.x = hw[4]; W.y = hw[5]; W.z = hw[6]; W.w = hw[7];
            *(uint4*)(Pb + q * 128 + p1 * 16) = W;
            W.x = lw[0]; W.y = lw[1]; W.z = lw[2]; W.w = lw[3];
            *(uint4*)(Pb + 8192 + q * 128 + p0 * 16) = W;
            W.x = lw[4]; W.y = lw[5]; W.z = lw[6]; W.w = lw[7];
            *(uint4*)(Pb + 8192 + q * 128 + p1 * 16) = W;
        }
        __syncthreads();   // S dead; P visible

        // stage G_j via async global->LDS (pre-swizzled linear 16KB)
        {
            const char* gs = Gp + (size_t)j * 16384 + wv * 4096 + lane * 16;
            #pragma unroll
            for (int k = 0; k < 4; k++)
                GLDS(gs + k * 1024, lds + wv * 4096 + k * 1024);
        }
        __syncthreads();

        // quadratic: y = P * G (3-term)
        f32x4 acc2[2][2];
        #pragma unroll
        for (int x = 0; x < 2; x++)
            #pragma unroll
            for (int y = 0; y < 2; y++) acc2[x][y] = (f32x4){0.f, 0.f, 0.f, 0.f};
        #pragma unroll
        for (int ch = 0; ch < 2; ch++) {
            short8 pah[2], pal[2], gbh[2], gbl[2];
            #pragma unroll
            for (int m2i = 0; m2i < 2; m2i++) {
                int q = 32 * wq + 16 * m2i + ln;
                int ph = ((ch * 4 + quad) + q) & 7;
                pah[m2i] = *(const short8*)(Pb + q * 128 + ph * 16);
                pal[m2i] = *(const short8*)(Pb + 8192 + q * 128 + ph * 16);
            }
            #pragma unroll
            for (int n2i = 0; n2i < 2; n2i++) {
                int u = 32 * wn + 16 * n2i + ln;
                int ph = ((ch * 4 + quad) + u) & 7;
                gbh[n2i] = *(const short8*)(lds + u * 128 + ph * 16);
                gbl[n2i] = *(const short8*)(lds + 8192 + u * 128 + ph * 16);
            }
            #pragma unroll
            for (int m2i = 0; m2i < 2; m2i++)
                #pragma unroll
                for (int n2i = 0; n2i < 2; n2i++) {
                    acc2[m2i][n2i] = __builtin_amdgcn_mfma_f32_16x16x32_bf16(pah[m2i], gbh[n2i], acc2[m2i][n2i], 0, 0, 0);
                    acc2[m2i][n2i] = __builtin_amdgcn_mfma_f32_16x16x32_bf16(pah[m2i], gbl[n2i], acc2[m2i][n2i], 0, 0, 0);
                    acc2[m2i][n2i] = __builtin_amdgcn_mfma_f32_16x16x32_bf16(pal[m2i], gbh[n2i], acc2[m2i][n2i], 0, 0, 0);
                }
        }
        __syncthreads();   // G reads done

        // yT[t][q0..q0+3] b128
        #pragma unroll
        for (int m2i = 0; m2i < 2; m2i++)
            #pragma unroll
            for (int n2i = 0; n2i < 2; n2i++) {
                int q0 = 32 * wq + 16 * m2i + quad * 4;
                int t  = 32 * wn + 16 * n2i + ln;
                *(f32x4*)(yT + t * SST + q0) = acc2[m2i][n2i];
            }
        __syncthreads();

        // fold: w2all[q] = sum_t y[q][t] * P[q][t]
        {
            const int q = tid >> 2, c = tid & 3;
            int p0 = (2 * c + q) & 7, p1 = (2 * c + 1 + q) & 7;
            uint4 H0 = *(const uint4*)(Pb + q * 128 + p0 * 16);
            uint4 H1 = *(const uint4*)(Pb + q * 128 + p1 * 16);
            uint4 L0 = *(const uint4*)(Pb + 8192 + q * 128 + p0 * 16);
            uint4 L1 = *(const uint4*)(Pb + 8192 + q * 128 + p1 * 16);
            uint hw[8] = {H0.x,H0.y,H0.z,H0.w, H1.x,H1.y,H1.z,H1.w};
            uint lw[8] = {L0.x,L0.y,L0.z,L0.w, L1.x,L1.y,L1.z,L1.w};
            float s = 0.f;
            #pragma unroll
            for (int e = 0; e < 8; e++) {
                float q0v = bf2f((ushort)(hw[e] & 0xFFFFu)) + bf2f((ushort)(lw[e] & 0xFFFFu));
                float q1v = bf2f((ushort)(hw[e] >> 16))     + bf2f((ushort)(lw[e] >> 16));
                s += q0v * yT[(16 * c + 2 * e) * SST + q];
                s += q1v * yT[(16 * c + 2 * e + 1) * SST + q];
            }
            s += __shfl_xor(s, 1);
            s += __shfl_xor(s, 2);
            if (c == 0) w2all[pr * 64 + q] = s;
        }
        __syncthreads();   // yT reads done; next pair may overwrite region 0 and Pb
    }

    // sim tail: wave wv handles pair wv
    {
        const int pr = wv;
        const int ii = i0 + (pr & 1), jj = j0 + (pr >> 1);
        float w2 = sqrtf(fmaxf(w2all[pr * 64 + lane], 0.f));
        float cosv = w12all[pr * 64 + lane] / fmaxf(w1g[ii * 64 + lane] * w2, EPSF);
        float e = __expf(T2 * cosv);
        #pragma unroll
        for (int off = 32; off; off >>= 1) e += __shfl_down(e, off);
        if (lane == 0) simval[ii * 64 + jj] = T3 * __logf(e);
    }
}

// ---------------- loss from the 64x64 sim matrix ----------------
__global__ __launch_bounds__(256) void loss_kernel(const float* __restrict__ val,
                                                   float* __restrict__ out) {
    __shared__ float v[4096];
    const int tid = threadIdx.x;
    #pragma unroll
    for (int k = 0; k < 4; k++)
        ((float4*)v)[tid + k * 256] = ((const float4*)val)[tid + k * 256];
    __syncthreads();
    if (tid < 64) {
        int i = tid;
        float rmax = -1e30f, cmax = -1e30f;
        for (int jj = 0; jj < 64; jj++) {
            rmax = fmaxf(rmax, v[i * 64 + jj]);
            cmax = fmaxf(cmax, v[jj * 64 + i]);
        }
        float rs = 0.f, cs = 0.f;
        for (int jj = 0; jj < 64; jj++) {
            rs += __expf(v[i * 64 + jj] - rmax);
            cs += __expf(v[jj * 64 + i] - cmax);
        }
        float rlse = rmax + __logf(rs);
        float clse = cmax + __logf(cs);
        float part = 2.f * v[i * 64 + i] - rlse - clse;
        #pragma unroll
        for (int off = 32; off; off >>= 1) part += __shfl_down(part, off);
        if (i == 0) out[0] = -part / 128.f;
    }
}

extern "C" void kernel_launch(void* const* d_in, const int* in_sizes, int n_in,
                              void* d_out, int out_size, void* d_ws, size_t ws_size,
                              hipStream_t stream) {
    (void)in_sizes; (void)n_in; (void)out_size; (void)ws_size;
    const float* ecg  = (const float*)d_in[0];
    const float* sent = (const float*)d_in[1];
    float* out = (float*)d_out;

    char* ws = (char*)d_ws;
    float* w1v  = (float*)ws;                     // 16 KB
    float* simv = (float*)(ws + 16384);           // 16 KB
    char* EH = ws + 32768;                        // 4 MB each
    char* EL = EH + (size_t)64 * 65536;
    char* SH = EL + (size_t)64 * 65536;
    char* SL = SH + (size_t)64 * 65536;
    char* Gp = SL + (size_t)64 * 65536;           // 1 MB

    prep_kernel <<<256, 256, 0, stream>>>(ecg, sent, EH, EL, SH, SL, w1v);
    gprep_kernel<<<64,  256, 0, stream>>>(EH, EL, Gp);
    pair_kernel <<<1024, 256, 0, stream>>>(EH, EL, SH, SL, Gp, w1v, simv, out);
    loss_kernel <<<1,   256, 0, stream>>>(simv, out);
}

// Round 6
// 158.713 us; speedup vs baseline: 1.0188x; 1.0188x over previous
//
#include <hip/hip_runtime.h>
#include <math.h>

typedef __attribute__((ext_vector_type(8))) short short8;
typedef __attribute__((ext_vector_type(4))) float f32x4;
typedef unsigned int uint;
typedef unsigned short ushort;

#define T1 4.0f
#define T2 5.0f
#define T3 10.0f
#define EPSF 1e-8f

__device__ inline ushort f2bf(float x) {
    union { float f; uint u; } a; a.f = x;
    uint r = a.u + 0x7FFFu + ((a.u >> 16) & 1u);
    return (ushort)(r >> 16);
}
__device__ inline float bf2f(ushort h) {
    union { uint u; float f; } a; a.u = ((uint)h) << 16;
    return a.f;
}

// async global->LDS, 16B per lane; LDS dest is wave-uniform base + lane*16
#define GLDS(gsrc, ldst) \
    __builtin_amdgcn_global_load_lds( \
        (const __attribute__((address_space(1))) uint*)(gsrc), \
        (__attribute__((address_space(3))) uint*)(ldst), 16, 0, 0)

// ---------------- fused prep: planes + G + w1 ----------------
// Plane layout per idx: [kc 0..15][r 0..63][4 chunks 16B, logical c at phys (c+(r>>1))&3].
// G layout: row t 128B, element u at phys chunk ((u>>3)+t)&7; lo plane +8192.
// Blocks 0..63: ecg -> EH/EL planes + G_j (MFMA).  Blocks 64..127: sent -> SH/SL + w1.
__global__ __launch_bounds__(256) void prepg_kernel(
        const float* __restrict__ ecg, const float* __restrict__ sent,
        char* __restrict__ EH, char* __restrict__ EL,
        char* __restrict__ SH, char* __restrict__ SL,
        char* __restrict__ Gp, float* __restrict__ w1) {
    __shared__ __align__(16) char plds[8192];
    const int bid = blockIdx.x;
    const int tid = threadIdx.x;
    const int r = tid >> 2, cq = tid & 3;
    const int phys = (cq + (r >> 1)) & 3;

    if (bid < 64) {
        // ---- E block: convert + Gram via 3-term bf16 MFMA ----
        const int j = bid;
        const float* src = ecg + (size_t)j * 32768;
        char* dh = EH + (size_t)j * 65536;
        char* dl = EL + (size_t)j * 65536;
        const int wv = tid >> 6, lane = tid & 63;
        const int wq = wv >> 1, wn = wv & 1;
        const int quad = lane >> 4, ln = lane & 15;
        int ao[2], bo[2];
        #pragma unroll
        for (int mi = 0; mi < 2; mi++) {
            int R = 32 * wq + 16 * mi + ln;
            ao[mi] = R * 64 + ((quad + (R >> 1)) & 3) * 16;
        }
        #pragma unroll
        for (int ni = 0; ni < 2; ni++) {
            int R = 32 * wn + 16 * ni + ln;
            bo[ni] = R * 64 + ((quad + (R >> 1)) & 3) * 16;
        }
        f32x4 acc[2][2];
        #pragma unroll
        for (int a = 0; a < 2; a++)
            #pragma unroll
            for (int b = 0; b < 2; b++) acc[a][b] = (f32x4){0.f, 0.f, 0.f, 0.f};

        for (int kc = 0; kc < 16; kc++) {
            const float4* p = (const float4*)(src + (size_t)r * 512 + kc * 32 + cq * 8);
            float4 va = p[0], vb = p[1];
            ushort h0 = f2bf(va.x), h1 = f2bf(va.y), h2 = f2bf(va.z), h3 = f2bf(va.w);
            ushort h4 = f2bf(vb.x), h5 = f2bf(vb.y), h6 = f2bf(vb.z), h7 = f2bf(vb.w);
            uint4 H;
            H.x = (uint)h0 | ((uint)h1 << 16); H.y = (uint)h2 | ((uint)h3 << 16);
            H.z = (uint)h4 | ((uint)h5 << 16); H.w = (uint)h6 | ((uint)h7 << 16);
            uint4 L;
            L.x = (uint)f2bf(va.x - bf2f(h0)) | ((uint)f2bf(va.y - bf2f(h1)) << 16);
            L.y = (uint)f2bf(va.z - bf2f(h2)) | ((uint)f2bf(va.w - bf2f(h3)) << 16);
            L.z = (uint)f2bf(vb.x - bf2f(h4)) | ((uint)f2bf(vb.y - bf2f(h5)) << 16);
            L.w = (uint)f2bf(vb.z - bf2f(h6)) | ((uint)f2bf(vb.w - bf2f(h7)) << 16);
            __syncthreads();   // prev kc frag reads done
            *(uint4*)(plds + r * 64 + phys * 16)        = H;
            *(uint4*)(plds + 4096 + r * 64 + phys * 16) = L;
            *(uint4*)(dh + (size_t)kc * 4096 + r * 64 + phys * 16) = H;
            *(uint4*)(dl + (size_t)kc * 4096 + r * 64 + phys * 16) = L;
            __syncthreads();
            short8 ah[2], al[2], bh[2], bl[2];
            #pragma unroll
            for (int mi = 0; mi < 2; mi++) {
                ah[mi] = *(const short8*)(plds + ao[mi]);
                al[mi] = *(const short8*)(plds + 4096 + ao[mi]);
            }
            #pragma unroll
            for (int ni = 0; ni < 2; ni++) {
                bh[ni] = *(const short8*)(plds + bo[ni]);
                bl[ni] = *(const short8*)(plds + 4096 + bo[ni]);
            }
            #pragma unroll
            for (int mi = 0; mi < 2; mi++)
                #pragma unroll
                for (int ni = 0; ni < 2; ni++) {
                    acc[mi][ni] = __builtin_amdgcn_mfma_f32_16x16x32_bf16(ah[mi], bh[ni], acc[mi][ni], 0, 0, 0);
                    acc[mi][ni] = __builtin_amdgcn_mfma_f32_16x16x32_bf16(ah[mi], bl[ni], acc[mi][ni], 0, 0, 0);
                    acc[mi][ni] = __builtin_amdgcn_mfma_f32_16x16x32_bf16(al[mi], bh[ni], acc[mi][ni], 0, 0, 0);
                }
        }
        #pragma unroll
        for (int mi = 0; mi < 2; mi++)
            #pragma unroll
            for (int ni = 0; ni < 2; ni++)
                #pragma unroll
                for (int rr = 0; rr < 4; rr++) {
                    int t = 32 * wq + 16 * mi + quad * 4 + rr;
                    int u = 32 * wn + 16 * ni + ln;
                    float g = acc[mi][ni][rr];
                    ushort h = f2bf(g);
                    ushort l = f2bf(g - bf2f(h));
                    char* base = Gp + (size_t)j * 16384 + t * 128 + (((u >> 3) + t) & 7) * 16 + (u & 7) * 2;
                    *(ushort*)base = h;
                    *(ushort*)(base + 8192) = l;
                }
    } else {
        // ---- S block: convert + w1 ----
        const int idx = bid - 64;
        const float* src = sent + (size_t)idx * 32768;
        char* dh = SH + (size_t)idx * 65536;
        char* dl = SL + (size_t)idx * 65536;
        float s2 = 0.f;
        for (int kc = 0; kc < 16; kc++) {
            const float4* p = (const float4*)(src + (size_t)r * 512 + kc * 32 + cq * 8);
            float4 va = p[0], vb = p[1];
            s2 += va.x * va.x + va.y * va.y + va.z * va.z + va.w * va.w +
                  vb.x * vb.x + vb.y * vb.y + vb.z * vb.z + vb.w * vb.w;
            ushort h0 = f2bf(va.x), h1 = f2bf(va.y), h2 = f2bf(va.z), h3 = f2bf(va.w);
            ushort h4 = f2bf(vb.x), h5 = f2bf(vb.y), h6 = f2bf(vb.z), h7 = f2bf(vb.w);
            uint4 H;
            H.x = (uint)h0 | ((uint)h1 << 16); H.y = (uint)h2 | ((uint)h3 << 16);
            H.z = (uint)h4 | ((uint)h5 << 16); H.w = (uint)h6 | ((uint)h7 << 16);
            uint4 L;
            L.x = (uint)f2bf(va.x - bf2f(h0)) | ((uint)f2bf(va.y - bf2f(h1)) << 16);
            L.y = (uint)f2bf(va.z - bf2f(h2)) | ((uint)f2bf(va.w - bf2f(h3)) << 16);
            L.z = (uint)f2bf(vb.x - bf2f(h4)) | ((uint)f2bf(vb.y - bf2f(h5)) << 16);
            L.w = (uint)f2bf(vb.z - bf2f(h6)) | ((uint)f2bf(vb.w - bf2f(h7)) << 16);
            *(uint4*)(dh + (size_t)kc * 4096 + r * 64 + phys * 16) = H;
            *(uint4*)(dl + (size_t)kc * 4096 + r * 64 + phys * 16) = L;
        }
        ((float*)plds)[tid] = s2;
        __syncthreads();
        if (tid < 64) {
            const float* q = (const float*)plds + tid * 4;
            w1[idx * 64 + tid] = sqrtf(q[0] + q[1] + q[2] + q[3]);
        }
    }
}

// ---------------- main: one block per 2x2 pairs (128x128 GEMM1 tile) ----------------
__global__ __launch_bounds__(256, 4) void pair_kernel(
        const char* __restrict__ EH, const char* __restrict__ EL,
        const char* __restrict__ SH, const char* __restrict__ SL,
        const char* __restrict__ Gp, const float* __restrict__ w1g,
        float* __restrict__ simval, float* __restrict__ out) {

    // lds: GEMM staging [EH 8K|EL 8K|SH 8K|SL 8K]=32K;
    // post-GEMM: SsT rotated (64 rows x 256B) at 0..16K, Phi (64 x 128B) at 16384..24576
    __shared__ __align__(16) char lds[32768];
    __shared__ __align__(16) float mz[64];
    __shared__ float w12all[256], w2all[256];
    __shared__ float w2part[64 * 9];

    const int tid = threadIdx.x;
    const int bn = blockIdx.x;
    const int xcd = bn & 7, slot = bn >> 3;
    const int T = xcd * 8 + (slot >> 4);
    const int wp = slot & 15;
    const int bi = (T >> 3) * 4 + (wp >> 2);
    const int bj = (T & 7) * 4 + (wp & 3);
    const int i0 = bi * 2, j0 = bj * 2;

    const int wv = tid >> 6, lane = tid & 63;
    const int wq = wv >> 1, wn = wv & 1;
    const int quad = lane >> 4, ln = lane & 15;

    int aoff[4], boff[4];
    #pragma unroll
    for (int mi = 0; mi < 4; mi++) {
        int R = 64 * (mi >> 1) + 32 * wq + 16 * (mi & 1) + ln;
        aoff[mi] = R * 64 + ((quad + (R >> 1)) & 3) * 16;
    }
    #pragma unroll
    for (int ni = 0; ni < 4; ni++) {
        int R = 64 * (ni >> 1) + 32 * wn + 16 * (ni & 1) + ln;
        boff[ni] = 16384 + R * 64 + ((quad + (R >> 1)) & 3) * 16;
    }

    const char* gA; const char* gB; int ldoff;
    if (wv == 0)      { gA = EH + (size_t)j0 * 65536;       gB = EH + (size_t)(j0 + 1) * 65536; ldoff = 0; }
    else if (wv == 1) { gA = EL + (size_t)j0 * 65536;       gB = EL + (size_t)(j0 + 1) * 65536; ldoff = 8192; }
    else if (wv == 2) { gA = SH + (size_t)i0 * 65536;       gB = SH + (size_t)(i0 + 1) * 65536; ldoff = 16384; }
    else              { gA = SL + (size_t)i0 * 65536;       gB = SL + (size_t)(i0 + 1) * 65536; ldoff = 24576; }
    gA += lane * 16; gB += lane * 16;

    f32x4 acc[4][4];
    #pragma unroll
    for (int a = 0; a < 4; a++)
        #pragma unroll
        for (int b = 0; b < 4; b++) acc[a][b] = (f32x4){0.f, 0.f, 0.f, 0.f};

    for (int kc = 0; kc < 16; kc++) {
        #pragma unroll
        for (int n = 0; n < 4; n++) GLDS(gA + n * 1024, lds + ldoff + n * 1024);
        #pragma unroll
        for (int n = 0; n < 4; n++) GLDS(gB + n * 1024, lds + ldoff + 4096 + n * 1024);
        gA += 4096; gB += 4096;
        __syncthreads();
        short8 bh[4], bl[4];
        #pragma unroll
        for (int ni = 0; ni < 4; ni++) {
            bh[ni] = *(const short8*)(lds + boff[ni]);
            bl[ni] = *(const short8*)(lds + boff[ni] + 8192);
        }
        #pragma unroll
        for (int mi = 0; mi < 4; mi++) {
            short8 ah = *(const short8*)(lds + aoff[mi]);
            short8 al = *(const short8*)(lds + aoff[mi] + 8192);
            #pragma unroll
            for (int ni = 0; ni < 4; ni++) {
                acc[mi][ni] = __builtin_amdgcn_mfma_f32_16x16x32_bf16(ah, bh[ni], acc[mi][ni], 0, 0, 0);
                acc[mi][ni] = __builtin_amdgcn_mfma_f32_16x16x32_bf16(ah, bl[ni], acc[mi][ni], 0, 0, 0);
                acc[mi][ni] = __builtin_amdgcn_mfma_f32_16x16x32_bf16(al, bh[ni], acc[mi][ni], 0, 0, 0);
            }
        }
        __syncthreads();
    }

    char* Phi = lds + 16384;

    #pragma unroll
    for (int pr = 0; pr < 4; pr++) {
        const int a = pr >> 1, b = pr & 1;
        const int i = i0 + b, j = j0 + a;
        const char* Gpj = Gp + (size_t)j * 16384;

        // C-write into rotated SsT: element [q][s] at q*256 + ((s/4+q)&15)*16
        #pragma unroll
        for (int dm = 0; dm < 2; dm++)
            #pragma unroll
            for (int dn = 0; dn < 2; dn++) {
                int s0 = 32 * wq + 16 * dm + quad * 4;
                int q  = 32 * wn + 16 * dn + ln;
                *(f32x4*)(lds + q * 256 + (((s0 >> 2) + q) & 15) * 16) = acc[2 * a + dm][2 * b + dn];
            }
        __syncthreads();   // A

        // softmax1 stats over q (conflict-free rotated column walk)
        {
            const int s = tid >> 2, c = tid & 3;
            float vv[16]; float m = -1e30f;
            #pragma unroll
            for (int t = 0; t < 16; t++) {
                int q = 16 * c + t;
                vv[t] = *(const float*)(lds + q * 256 + ((((s >> 2) + q) & 15) << 4) + ((s & 3) << 2));
                m = fmaxf(m, vv[t]);
            }
            m = fmaxf(m, __shfl_xor(m, 1));
            m = fmaxf(m, __shfl_xor(m, 2));
            float sum = 0.f;
            #pragma unroll
            for (int t = 0; t < 16; t++) sum += __expf(vv[t] - m);
            sum += __shfl_xor(sum, 1);
            sum += __shfl_xor(sum, 2);
            if (c == 0) mz[s] = m + __logf(sum);
        }
        __syncthreads();   // B

        // softmax2 over s: P[q][s]; w12 fold; att_maps; pack P hi only
        {
            const int q = tid >> 2, c = tid & 3;
            float sc[16], at[16], mzv[16];
            #pragma unroll
            for (int k = 0; k < 4; k++)
                *(f32x4*)(sc + 4 * k) = *(const f32x4*)(lds + q * 256 + (((4 * c + k) + q) & 15) * 16);
            #pragma unroll
            for (int k = 0; k < 4; k++)
                *(f32x4*)(mzv + 4 * k) = *(const f32x4*)(mz + 16 * c + 4 * k);
            float m2 = -1e30f;
            #pragma unroll
            for (int t = 0; t < 16; t++) {
                at[t] = __expf(sc[t] - mzv[t]);
                m2 = fmaxf(m2, T1 * at[t]);
            }
            m2 = fmaxf(m2, __shfl_xor(m2, 1));
            m2 = fmaxf(m2, __shfl_xor(m2, 2));
            float sum = 0.f;
            #pragma unroll
            for (int t = 0; t < 16; t++) { at[t] = __expf(T1 * at[t] - m2); sum += at[t]; }
            sum += __shfl_xor(sum, 1);
            sum += __shfl_xor(sum, 2);
            float inv = 1.f / sum;
            float p12 = 0.f;
            #pragma unroll
            for (int t = 0; t < 16; t++) { at[t] *= inv; p12 += at[t] * sc[t]; }
            p12 += __shfl_xor(p12, 1);
            p12 += __shfl_xor(p12, 2);
            if (c == 0) w12all[pr * 64 + q] = p12;

            if (i == j) {
                float* om = out + 1 + (size_t)i * 4096;
                #pragma unroll
                for (int t = 0; t < 16; t++) om[q * 64 + c * 16 + t] = at[t];
            }

            uint hw[8];
            #pragma unroll
            for (int e = 0; e < 8; e++)
                hw[e] = (uint)f2bf(at[2 * e]) | ((uint)f2bf(at[2 * e + 1]) << 16);
            int p0 = (2 * c + q) & 7, p1 = (2 * c + 1 + q) & 7;
            uint4 W;
            W.x = hw[0]; W.y = hw[1]; W.z = hw[2]; W.w = hw[3];
            *(uint4*)(Phi + q * 128 + p0 * 16) = W;
            W.x = hw[4]; W.y = hw[5]; W.z = hw[6]; W.w = hw[7];
            *(uint4*)(Phi + q * 128 + p1 * 16) = W;
        }
        __syncthreads();   // C

        // quadratic: y = P_hi * (G_hi + G_lo); G frags straight from global (L2-hot)
        f32x4 acc2[2][2];
        #pragma unroll
        for (int x = 0; x < 2; x++)
            #pragma unroll
            for (int y = 0; y < 2; y++) acc2[x][y] = (f32x4){0.f, 0.f, 0.f, 0.f};
        #pragma unroll
        for (int ch = 0; ch < 2; ch++) {
            short8 pah[2], gbh[2], gbl[2];
            #pragma unroll
            for (int m2i = 0; m2i < 2; m2i++) {
                int q = 32 * wq + 16 * m2i + ln;
                pah[m2i] = *(const short8*)(Phi + q * 128 + (((ch * 4 + quad) + q) & 7) * 16);
            }
            #pragma unroll
            for (int n2i = 0; n2i < 2; n2i++) {
                int u = 32 * wn + 16 * n2i + ln;
                int ph = ((ch * 4 + quad) + u) & 7;
                gbh[n2i] = *(const short8*)(Gpj + u * 128 + ph * 16);
                gbl[n2i] = *(const short8*)(Gpj + 8192 + u * 128 + ph * 16);
            }
            #pragma unroll
            for (int m2i = 0; m2i < 2; m2i++)
                #pragma unroll
                for (int n2i = 0; n2i < 2; n2i++) {
                    acc2[m2i][n2i] = __builtin_amdgcn_mfma_f32_16x16x32_bf16(pah[m2i], gbh[n2i], acc2[m2i][n2i], 0, 0, 0);
                    acc2[m2i][n2i] = __builtin_amdgcn_mfma_f32_16x16x32_bf16(pah[m2i], gbl[n2i], acc2[m2i][n2i], 0, 0, 0);
                }
        }

        // fold from registers: w2part[q][wn*4 + ln/4] = partial sum_t y*P
        #pragma unroll
        for (int m2i = 0; m2i < 2; m2i++)
            #pragma unroll
            for (int rr = 0; rr < 4; rr++) {
                int q = 32 * wq + 16 * m2i + quad * 4 + rr;
                float p = 0.f;
                #pragma unroll
                for (int n2i = 0; n2i < 2; n2i++) {
                    int t = 32 * wn + 16 * n2i + ln;
                    float Pv = bf2f(*(const ushort*)(Phi + q * 128 +
                                     ((((t >> 3) + q) & 7) << 4) + ((t & 7) << 1)));
                    p += acc2[m2i][n2i][rr] * Pv;
                }
                p += __shfl_xor(p, 1);
                p += __shfl_xor(p, 2);
                if ((ln & 3) == 0) w2part[q * 9 + wn * 4 + (ln >> 2)] = p;
            }
        __syncthreads();   // D

        if (tid < 64) {
            const float* wp9 = w2part + tid * 9;
            w2all[pr * 64 + tid] = wp9[0] + wp9[1] + wp9[2] + wp9[3] +
                                   wp9[4] + wp9[5] + wp9[6] + wp9[7];
        }
        // no barrier: next pair's w2part writes are ordered by barriers A'/B'/C'
    }
    __syncthreads();

    // sim tail: wave wv handles pair wv
    {
        const int pr = wv;
        const int ii = i0 + (pr & 1), jj = j0 + (pr >> 1);
        float w2 = sqrtf(fmaxf(w2all[pr * 64 + lane], 0.f));
        float cosv = w12all[pr * 64 + lane] / fmaxf(w1g[ii * 64 + lane] * w2, EPSF);
        float e = __expf(T2 * cosv);
        #pragma unroll
        for (int off = 32; off; off >>= 1) e += __shfl_down(e, off);
        if (lane == 0) simval[ii * 64 + jj] = T3 * __logf(e);
    }
}

// ---------------- loss from the 64x64 sim matrix ----------------
__global__ __launch_bounds__(256) void loss_kernel(const float* __restrict__ val,
                                                   float* __restrict__ out) {
    __shared__ float v[4096];
    const int tid = threadIdx.x;
    #pragma unroll
    for (int k = 0; k < 4; k++)
        ((float4*)v)[tid + k * 256] = ((const float4*)val)[tid + k * 256];
    __syncthreads();
    if (tid < 64) {
        int i = tid;
        float rmax = -1e30f, cmax = -1e30f;
        for (int jj = 0; jj < 64; jj++) {
            rmax = fmaxf(rmax, v[i * 64 + jj]);
            cmax = fmaxf(cmax, v[jj * 64 + i]);
        }
        float rs = 0.f, cs = 0.f;
        for (int jj = 0; jj < 64; jj++) {
            rs += __expf(v[i * 64 + jj] - rmax);
            cs += __expf(v[jj * 64 + i] - cmax);
        }
        float rlse = rmax + __logf(rs);
        float clse = cmax + __logf(cs);
        float part = 2.f * v[i * 64 + i] - rlse - clse;
        #pragma unroll
        for (int off = 32; off; off >>= 1) part += __shfl_down(part, off);
        if (i == 0) out[0] = -part / 128.f;
    }
}

extern "C" void kernel_launch(void* const* d_in, const int* in_sizes, int n_in,
                              void* d_out, int out_size, void* d_ws, size_t ws_size,
                              hipStream_t stream) {
    (void)in_sizes; (void)n_in; (void)out_size; (void)ws_size;
    const float* ecg  = (const float*)d_in[0];
    const float* sent = (const float*)d_in[1];
    float* out = (float*)d_out;

    char* ws = (char*)d_ws;
    float* w1v  = (float*)ws;                     // 16 KB
    float* simv = (float*)(ws + 16384);           // 16 KB
    char* EH = ws + 32768;                        // 4 MB each
    char* EL = EH + (size_t)64 * 65536;
    char* SH = EL + (size_t)64 * 65536;
    char* SL = SH + (size_t)64 * 65536;
    char* Gp = SL + (size_t)64 * 65536;           // 1 MB

    prepg_kernel<<<128,  256, 0, stream>>>(ecg, sent, EH, EL, SH, SL, Gp, w1v);
    pair_kernel <<<1024, 256, 0, stream>>>(EH, EL, SH, SL, Gp, w1v, simv, out);
    loss_kernel <<<1,    256, 0, stream>>>(simv, out);
}

// Round 8
// 156.886 us; speedup vs baseline: 1.0306x; 1.0116x over previous
//
#include <hip/hip_runtime.h>
#include <math.h>

typedef __attribute__((ext_vector_type(8))) short short8;
typedef __attribute__((ext_vector_type(4))) float f32x4;
typedef unsigned int uint;
typedef unsigned short ushort;

#define T1 4.0f
#define T2 5.0f
#define T3 10.0f
#define EPSF 1e-8f

__device__ inline ushort f2bf(float x) {
    union { float f; uint u; } a; a.f = x;
    uint r = a.u + 0x7FFFu + ((a.u >> 16) & 1u);
    return (ushort)(r >> 16);
}
__device__ inline float bf2f(ushort h) {
    union { uint u; float f; } a; a.u = ((uint)h) << 16;
    return a.f;
}

// async global->LDS, 16B per lane; LDS dest is wave-uniform base + lane*16
#define GLDS(gsrc, ldst) \
    __builtin_amdgcn_global_load_lds( \
        (const __attribute__((address_space(1))) uint*)(gsrc), \
        (__attribute__((address_space(3))) uint*)(ldst), 16, 0, 0)

// ---------------- fused prep: planes + G + w1 ----------------
// Plane layout per idx: [kc 0..15][r 0..63][4 chunks 16B, logical c at phys (c+(r>>1))&3].
// G layout: row t 128B, element u at phys chunk ((u>>3)+t)&7; lo plane +8192.
__global__ __launch_bounds__(256) void prepg_kernel(
        const float* __restrict__ ecg, const float* __restrict__ sent,
        char* __restrict__ EH, char* __restrict__ EL,
        char* __restrict__ SH, char* __restrict__ SL,
        char* __restrict__ Gp, float* __restrict__ w1) {
    __shared__ __align__(16) char plds[8192];
    const int bid = blockIdx.x;
    const int tid = threadIdx.x;
    const int r = tid >> 2, cq = tid & 3;
    const int phys = (cq + (r >> 1)) & 3;

    if (bid < 64) {
        const int j = bid;
        const float* src = ecg + (size_t)j * 32768;
        char* dh = EH + (size_t)j * 65536;
        char* dl = EL + (size_t)j * 65536;
        const int wv = tid >> 6, lane = tid & 63;
        const int wq = wv >> 1, wn = wv & 1;
        const int quad = lane >> 4, ln = lane & 15;
        int ao[2], bo[2];
        #pragma unroll
        for (int mi = 0; mi < 2; mi++) {
            int R = 32 * wq + 16 * mi + ln;
            ao[mi] = R * 64 + ((quad + (R >> 1)) & 3) * 16;
        }
        #pragma unroll
        for (int ni = 0; ni < 2; ni++) {
            int R = 32 * wn + 16 * ni + ln;
            bo[ni] = R * 64 + ((quad + (R >> 1)) & 3) * 16;
        }
        f32x4 acc[2][2];
        #pragma unroll
        for (int a = 0; a < 2; a++)
            #pragma unroll
            for (int b = 0; b < 2; b++) acc[a][b] = (f32x4){0.f, 0.f, 0.f, 0.f};

        for (int kc = 0; kc < 16; kc++) {
            const float4* p = (const float4*)(src + (size_t)r * 512 + kc * 32 + cq * 8);
            float4 va = p[0], vb = p[1];
            ushort h0 = f2bf(va.x), h1 = f2bf(va.y), h2 = f2bf(va.z), h3 = f2bf(va.w);
            ushort h4 = f2bf(vb.x), h5 = f2bf(vb.y), h6 = f2bf(vb.z), h7 = f2bf(vb.w);
            uint4 H;
            H.x = (uint)h0 | ((uint)h1 << 16); H.y = (uint)h2 | ((uint)h3 << 16);
            H.z = (uint)h4 | ((uint)h5 << 16); H.w = (uint)h6 | ((uint)h7 << 16);
            uint4 L;
            L.x = (uint)f2bf(va.x - bf2f(h0)) | ((uint)f2bf(va.y - bf2f(h1)) << 16);
            L.y = (uint)f2bf(va.z - bf2f(h2)) | ((uint)f2bf(va.w - bf2f(h3)) << 16);
            L.z = (uint)f2bf(vb.x - bf2f(h4)) | ((uint)f2bf(vb.y - bf2f(h5)) << 16);
            L.w = (uint)f2bf(vb.z - bf2f(h6)) | ((uint)f2bf(vb.w - bf2f(h7)) << 16);
            __syncthreads();
            *(uint4*)(plds + r * 64 + phys * 16)        = H;
            *(uint4*)(plds + 4096 + r * 64 + phys * 16) = L;
            *(uint4*)(dh + (size_t)kc * 4096 + r * 64 + phys * 16) = H;
            *(uint4*)(dl + (size_t)kc * 4096 + r * 64 + phys * 16) = L;
            __syncthreads();
            short8 ah[2], al[2], bh[2], bl[2];
            #pragma unroll
            for (int mi = 0; mi < 2; mi++) {
                ah[mi] = *(const short8*)(plds + ao[mi]);
                al[mi] = *(const short8*)(plds + 4096 + ao[mi]);
            }
            #pragma unroll
            for (int ni = 0; ni < 2; ni++) {
                bh[ni] = *(const short8*)(plds + bo[ni]);
                bl[ni] = *(const short8*)(plds + 4096 + bo[ni]);
            }
            #pragma unroll
            for (int mi = 0; mi < 2; mi++)
                #pragma unroll
                for (int ni = 0; ni < 2; ni++) {
                    acc[mi][ni] = __builtin_amdgcn_mfma_f32_16x16x32_bf16(ah[mi], bh[ni], acc[mi][ni], 0, 0, 0);
                    acc[mi][ni] = __builtin_amdgcn_mfma_f32_16x16x32_bf16(ah[mi], bl[ni], acc[mi][ni], 0, 0, 0);
                    acc[mi][ni] = __builtin_amdgcn_mfma_f32_16x16x32_bf16(al[mi], bh[ni], acc[mi][ni], 0, 0, 0);
                }
        }
        #pragma unroll
        for (int mi = 0; mi < 2; mi++)
            #pragma unroll
            for (int ni = 0; ni < 2; ni++)
                #pragma unroll
                for (int rr = 0; rr < 4; rr++) {
                    int t = 32 * wq + 16 * mi + quad * 4 + rr;
                    int u = 32 * wn + 16 * ni + ln;
                    float g = acc[mi][ni][rr];
                    ushort h = f2bf(g);
                    ushort l = f2bf(g - bf2f(h));
                    char* base = Gp + (size_t)j * 16384 + t * 128 + (((u >> 3) + t) & 7) * 16 + (u & 7) * 2;
                    *(ushort*)base = h;
                    *(ushort*)(base + 8192) = l;
                }
    } else {
        const int idx = bid - 64;
        const float* src = sent + (size_t)idx * 32768;
        char* dh = SH + (size_t)idx * 65536;
        char* dl = SL + (size_t)idx * 65536;
        float s2 = 0.f;
        for (int kc = 0; kc < 16; kc++) {
            const float4* p = (const float4*)(src + (size_t)r * 512 + kc * 32 + cq * 8);
            float4 va = p[0], vb = p[1];
            s2 += va.x * va.x + va.y * va.y + va.z * va.z + va.w * va.w +
                  vb.x * vb.x + vb.y * vb.y + vb.z * vb.z + vb.w * vb.w;
            ushort h0 = f2bf(va.x), h1 = f2bf(va.y), h2 = f2bf(va.z), h3 = f2bf(va.w);
            ushort h4 = f2bf(vb.x), h5 = f2bf(vb.y), h6 = f2bf(vb.z), h7 = f2bf(vb.w);
            uint4 H;
            H.x = (uint)h0 | ((uint)h1 << 16); H.y = (uint)h2 | ((uint)h3 << 16);
            H.z = (uint)h4 | ((uint)h5 << 16); H.w = (uint)h6 | ((uint)h7 << 16);
            uint4 L;
            L.x = (uint)f2bf(va.x - bf2f(h0)) | ((uint)f2bf(va.y - bf2f(h1)) << 16);
            L.y = (uint)f2bf(va.z - bf2f(h2)) | ((uint)f2bf(va.w - bf2f(h3)) << 16);
            L.z = (uint)f2bf(vb.x - bf2f(h4)) | ((uint)f2bf(vb.y - bf2f(h5)) << 16);
            L.w = (uint)f2bf(vb.z - bf2f(h6)) | ((uint)f2bf(vb.w - bf2f(h7)) << 16);
            *(uint4*)(dh + (size_t)kc * 4096 + r * 64 + phys * 16) = H;
            *(uint4*)(dl + (size_t)kc * 4096 + r * 64 + phys * 16) = L;
        }
        ((float*)plds)[tid] = s2;
        __syncthreads();
        if (tid < 64) {
            const float* q = (const float*)plds + tid * 4;
            w1[idx * 64 + tid] = sqrtf(q[0] + q[1] + q[2] + q[3]);
        }
    }
}

// ---------------- main: one block per 2x2 pairs; j-outer shared-G phases ----------------
__global__ __launch_bounds__(256, 4) void pair_kernel(
        const char* __restrict__ EH, const char* __restrict__ EL,
        const char* __restrict__ SH, const char* __restrict__ SL,
        const char* __restrict__ Gp, const float* __restrict__ w1g,
        float* __restrict__ simval, float* __restrict__ out) {

    // lds: GEMM staging [EH|EL|SH|SL] 32K; post-GEMM: SsT rotated (64x256B) / G (16K) at 0..16K,
    // Phi2 (128 rows x 128B) at 16384..32768
    __shared__ __align__(16) char lds[32768];
    __shared__ __align__(16) float mz[64];
    __shared__ float w12all[256], w2all[256];
    __shared__ float w2part[128 * 9];

    const int tid = threadIdx.x;
    const int bn = blockIdx.x;
    const int xcd = bn & 7, slot = bn >> 3;
    const int T = xcd * 8 + (slot >> 4);
    const int wp = slot & 15;
    const int bi = (T >> 3) * 4 + (wp >> 2);
    const int bj = (T & 7) * 4 + (wp & 3);
    const int i0 = bi * 2, j0 = bj * 2;

    const int wv = tid >> 6, lane = tid & 63;
    const int wq = wv >> 1, wn = wv & 1;
    const int quad = lane >> 4, ln = lane & 15;

    int aoff[4], boff[4];
    #pragma unroll
    for (int mi = 0; mi < 4; mi++) {
        int R = 64 * (mi >> 1) + 32 * wq + 16 * (mi & 1) + ln;
        aoff[mi] = R * 64 + ((quad + (R >> 1)) & 3) * 16;
    }
    #pragma unroll
    for (int ni = 0; ni < 4; ni++) {
        int R = 64 * (ni >> 1) + 32 * wn + 16 * (ni & 1) + ln;
        boff[ni] = 16384 + R * 64 + ((quad + (R >> 1)) & 3) * 16;
    }

    const char* gA; const char* gB; int ldoff;
    if (wv == 0)      { gA = EH + (size_t)j0 * 65536;       gB = EH + (size_t)(j0 + 1) * 65536; ldoff = 0; }
    else if (wv == 1) { gA = EL + (size_t)j0 * 65536;       gB = EL + (size_t)(j0 + 1) * 65536; ldoff = 8192; }
    else if (wv == 2) { gA = SH + (size_t)i0 * 65536;       gB = SH + (size_t)(i0 + 1) * 65536; ldoff = 16384; }
    else              { gA = SL + (size_t)i0 * 65536;       gB = SL + (size_t)(i0 + 1) * 65536; ldoff = 24576; }
    gA += lane * 16; gB += lane * 16;

    f32x4 acc[4][4];
    #pragma unroll
    for (int a = 0; a < 4; a++)
        #pragma unroll
        for (int b = 0; b < 4; b++) acc[a][b] = (f32x4){0.f, 0.f, 0.f, 0.f};

    for (int kc = 0; kc < 16; kc++) {
        #pragma unroll
        for (int n = 0; n < 4; n++) GLDS(gA + n * 1024, lds + ldoff + n * 1024);
        #pragma unroll
        for (int n = 0; n < 4; n++) GLDS(gB + n * 1024, lds + ldoff + 4096 + n * 1024);
        gA += 4096; gB += 4096;
        __syncthreads();
        short8 bh[4], bl[4];
        #pragma unroll
        for (int ni = 0; ni < 4; ni++) {
            bh[ni] = *(const short8*)(lds + boff[ni]);
            bl[ni] = *(const short8*)(lds + boff[ni] + 8192);
        }
        #pragma unroll
        for (int mi = 0; mi < 4; mi++) {
            short8 ah = *(const short8*)(lds + aoff[mi]);
            short8 al = *(const short8*)(lds + aoff[mi] + 8192);
            #pragma unroll
            for (int ni = 0; ni < 4; ni++) {
                acc[mi][ni] = __builtin_amdgcn_mfma_f32_16x16x32_bf16(ah, bh[ni], acc[mi][ni], 0, 0, 0);
                acc[mi][ni] = __builtin_amdgcn_mfma_f32_16x16x32_bf16(ah, bl[ni], acc[mi][ni], 0, 0, 0);
                acc[mi][ni] = __builtin_amdgcn_mfma_f32_16x16x32_bf16(al, bh[ni], acc[mi][ni], 0, 0, 0);
            }
        }
        __syncthreads();
    }

    char* Pb = lds + 16384;   // 128 rows x 128B (b*8192 + q*128)

    #pragma unroll
    for (int a = 0; a < 2; a++) {
        const int j = j0 + a;

        // ---- per-i phases: scores -> softmaxes -> P pack (rows b*64+q of Pb) ----
        #pragma unroll
        for (int b = 0; b < 2; b++) {
            const int i = i0 + b;
            const int pr = 2 * a + b;

            // C-write rotated SsT: [q][s] at q*256 + ((s/4+q)&15)*16
            #pragma unroll
            for (int dm = 0; dm < 2; dm++)
                #pragma unroll
                for (int dn = 0; dn < 2; dn++) {
                    int s0 = 32 * wq + 16 * dm + quad * 4;
                    int q  = 32 * wn + 16 * dn + ln;
                    *(f32x4*)(lds + q * 256 + (((s0 >> 2) + q) & 15) * 16) = acc[2 * a + dm][2 * b + dn];
                }
            __syncthreads();   // A

            // softmax1 stats over q
            {
                const int s = tid >> 2, c = tid & 3;
                float vv[16]; float m = -1e30f;
                #pragma unroll
                for (int t = 0; t < 16; t++) {
                    int q = 16 * c + t;
                    vv[t] = *(const float*)(lds + q * 256 + ((((s >> 2) + q) & 15) << 4) + ((s & 3) << 2));
                    m = fmaxf(m, vv[t]);
                }
                m = fmaxf(m, __shfl_xor(m, 1));
                m = fmaxf(m, __shfl_xor(m, 2));
                float sum = 0.f;
                #pragma unroll
                for (int t = 0; t < 16; t++) sum += __expf(vv[t] - m);
                sum += __shfl_xor(sum, 1);
                sum += __shfl_xor(sum, 2);
                if (c == 0) mz[s] = m + __logf(sum);
            }
            __syncthreads();   // B

            // softmax2 over s; w12 fold; att_maps; pack P hi
            {
                const int q = tid >> 2, c = tid & 3;
                float sc[16], at[16], mzv[16];
                #pragma unroll
                for (int k = 0; k < 4; k++)
                    *(f32x4*)(sc + 4 * k) = *(const f32x4*)(lds + q * 256 + (((4 * c + k) + q) & 15) * 16);
                #pragma unroll
                for (int k = 0; k < 4; k++)
                    *(f32x4*)(mzv + 4 * k) = *(const f32x4*)(mz + 16 * c + 4 * k);
                float m2 = -1e30f;
                #pragma unroll
                for (int t = 0; t < 16; t++) {
                    at[t] = __expf(sc[t] - mzv[t]);
                    m2 = fmaxf(m2, T1 * at[t]);
                }
                m2 = fmaxf(m2, __shfl_xor(m2, 1));
                m2 = fmaxf(m2, __shfl_xor(m2, 2));
                float sum = 0.f;
                #pragma unroll
                for (int t = 0; t < 16; t++) { at[t] = __expf(T1 * at[t] - m2); sum += at[t]; }
                sum += __shfl_xor(sum, 1);
                sum += __shfl_xor(sum, 2);
                float inv = 1.f / sum;
                float p12 = 0.f;
                #pragma unroll
                for (int t = 0; t < 16; t++) { at[t] *= inv; p12 += at[t] * sc[t]; }
                p12 += __shfl_xor(p12, 1);
                p12 += __shfl_xor(p12, 2);
                if (c == 0) w12all[pr * 64 + q] = p12;

                if (i == j) {
                    float* om = out + 1 + (size_t)i * 4096;
                    #pragma unroll
                    for (int t = 0; t < 16; t++) om[q * 64 + c * 16 + t] = at[t];
                }

                uint hw[8];
                #pragma unroll
                for (int e = 0; e < 8; e++)
                    hw[e] = (uint)f2bf(at[2 * e]) | ((uint)f2bf(at[2 * e + 1]) << 16);
                int p0 = (2 * c + q) & 7, p1 = (2 * c + 1 + q) & 7;
                uint4 W;
                W.x = hw[0]; W.y = hw[1]; W.z = hw[2]; W.w = hw[3];
                *(uint4*)(Pb + b * 8192 + q * 128 + p0 * 16) = W;
                W.x = hw[4]; W.y = hw[5]; W.z = hw[6]; W.w = hw[7];
                *(uint4*)(Pb + b * 8192 + q * 128 + p1 * 16) = W;
            }
            __syncthreads();   // C
        }

        // ---- stage G_j (hi+lo 16KB) into region 0 via async GLDS ----
        {
            const char* gs = Gp + (size_t)j * 16384 + wv * 4096 + lane * 16;
            #pragma unroll
            for (int k = 0; k < 4; k++)
                GLDS(gs + k * 1024, lds + wv * 4096 + k * 1024);
        }
        __syncthreads();   // D (drains vmcnt)

        // ---- qgemm M=128: Y = P2 * (G_hi + G_lo); wave = (M-half wq, N-half wn) ----
        f32x4 acc2[4][2];
        #pragma unroll
        for (int x = 0; x < 4; x++)
            #pragma unroll
            for (int y = 0; y < 2; y++) acc2[x][y] = (f32x4){0.f, 0.f, 0.f, 0.f};
        #pragma unroll
        for (int ch = 0; ch < 2; ch++) {
            short8 pah[4], gbh[2], gbl[2];
            #pragma unroll
            for (int m2i = 0; m2i < 4; m2i++) {
                int rA = 64 * wq + 16 * m2i + ln;
                pah[m2i] = *(const short8*)(Pb + rA * 128 + (((ch * 4 + quad) + rA) & 7) * 16);
            }
            #pragma unroll
            for (int n2i = 0; n2i < 2; n2i++) {
                int u = 32 * wn + 16 * n2i + ln;
                int ph = ((ch * 4 + quad) + u) & 7;
                gbh[n2i] = *(const short8*)(lds + u * 128 + ph * 16);
                gbl[n2i] = *(const short8*)(lds + 8192 + u * 128 + ph * 16);
            }
            #pragma unroll
            for (int m2i = 0; m2i < 4; m2i++)
                #pragma unroll
                for (int n2i = 0; n2i < 2; n2i++) {
                    acc2[m2i][n2i] = __builtin_amdgcn_mfma_f32_16x16x32_bf16(pah[m2i], gbh[n2i], acc2[m2i][n2i], 0, 0, 0);
                    acc2[m2i][n2i] = __builtin_amdgcn_mfma_f32_16x16x32_bf16(pah[m2i], gbl[n2i], acc2[m2i][n2i], 0, 0, 0);
                }
        }

        // fold from registers: partial sum_t Y[r][t]*P[r][t]
        #pragma unroll
        for (int m2i = 0; m2i < 4; m2i++)
            #pragma unroll
            for (int rr = 0; rr < 4; rr++) {
                int rA = 64 * wq + 16 * m2i + quad * 4 + rr;
                float p = 0.f;
                #pragma unroll
                for (int n2i = 0; n2i < 2; n2i++) {
                    int t = 32 * wn + 16 * n2i + ln;
                    float Pv = bf2f(*(const ushort*)(Pb + rA * 128 +
                                     ((((t >> 3) + rA) & 7) << 4) + ((t & 7) << 1)));
                    p += acc2[m2i][n2i][rr] * Pv;
                }
                p += __shfl_xor(p, 1);
                p += __shfl_xor(p, 2);
                if ((ln & 3) == 0) w2part[rA * 9 + wn * 4 + (ln >> 2)] = p;
            }
        __syncthreads();   // E (also guards: G reads done before next a's C-write)

        if (tid < 128) {
            const float* wp9 = w2part + tid * 9;
            w2all[(2 * a + (tid >> 6)) * 64 + (tid & 63)] =
                wp9[0] + wp9[1] + wp9[2] + wp9[3] + wp9[4] + wp9[5] + wp9[6] + wp9[7];
        }
        // next a's C-write safe after barrier E; w2part not rewritten until after next D
    }
    __syncthreads();

    // sim tail: wave wv handles pair pr=wv (pr = 2a+b -> ii=i0+(pr&1), jj=j0+(pr>>1))
    {
        const int pr = wv;
        const int ii = i0 + (pr & 1), jj = j0 + (pr >> 1);
        float w2 = sqrtf(fmaxf(w2all[pr * 64 + lane], 0.f));
        float cosv = w12all[pr * 64 + lane] / fmaxf(w1g[ii * 64 + lane] * w2, EPSF);
        float e = __expf(T2 * cosv);
        #pragma unroll
        for (int off = 32; off; off >>= 1) e += __shfl_down(e, off);
        if (lane == 0) simval[ii * 64 + jj] = T3 * __logf(e);
    }
}

// ---------------- loss from the 64x64 sim matrix (separate launch = coherence point) ----------------
__global__ __launch_bounds__(256) void loss_kernel(const float* __restrict__ val,
                                                   float* __restrict__ out) {
    __shared__ float v[4096];
    const int tid = threadIdx.x;
    #pragma unroll
    for (int k = 0; k < 4; k++)
        ((float4*)v)[tid + k * 256] = ((const float4*)val)[tid + k * 256];
    __syncthreads();
    if (tid < 64) {
        int i = tid;
        float rmax = -1e30f, cmax = -1e30f;
        for (int jj = 0; jj < 64; jj++) {
            rmax = fmaxf(rmax, v[i * 64 + jj]);
            cmax = fmaxf(cmax, v[jj * 64 + i]);
        }
        float rs = 0.f, cs = 0.f;
        for (int jj = 0; jj < 64; jj++) {
            rs += __expf(v[i * 64 + jj] - rmax);
            cs += __expf(v[jj * 64 + i] - cmax);
        }
        float rlse = rmax + __logf(rs);
        float clse = cmax + __logf(cs);
        float part = 2.f * v[i * 64 + i] - rlse - clse;
        #pragma unroll
        for (int off = 32; off; off >>= 1) part += __shfl_down(part, off);
        if (i == 0) out[0] = -part / 128.f;
    }
}

extern "C" void kernel_launch(void* const* d_in, const int* in_sizes, int n_in,
                              void* d_out, int out_size, void* d_ws, size_t ws_size,
                              hipStream_t stream) {
    (void)in_sizes; (void)n_in; (void)out_size; (void)ws_size;
    const float* ecg  = (const float*)d_in[0];
    const float* sent = (const float*)d_in[1];
    float* out = (float*)d_out;

    char* ws = (char*)d_ws;
    float* w1v  = (float*)ws;                     // 16 KB
    float* simv = (float*)(ws + 16384);           // 16 KB
    char* EH = ws + 65536;                        // 4 MB each
    char* EL = EH + (size_t)64 * 65536;
    char* SH = EL + (size_t)64 * 65536;
    char* SL = SH + (size_t)64 * 65536;
    char* Gp = SL + (size_t)64 * 65536;           // 1 MB

    prepg_kernel<<<128,  256, 0, stream>>>(ecg, sent, EH, EL, SH, SL, Gp, w1v);
    pair_kernel <<<1024, 256, 0, stream>>>(EH, EL, SH, SL, Gp, w1v, simv, out);
    loss_kernel <<<1,    256, 0, stream>>>(simv, out);
}